// Round 13
// baseline (1396.927 us; speedup 1.0000x reference)
//
#include <hip/hip_runtime.h>
#include <math.h>

#define BATCHN 256
#define HDIM 512
#define ZDIM 128
#define NGRID 32
#define ABDIM 128
#define IMGSZ 16384   // 128*128
#define ENCIN 2560
#define G3 1536
#define SLAB (BATCHN*G3)

typedef __attribute__((ext_vector_type(8))) short short8;
typedef __attribute__((ext_vector_type(4))) float f32x4;

__device__ __forceinline__ float sigmoidf_(float x){ return 1.0f/(1.0f+expf(-x)); }

__device__ __forceinline__ ushort f2bf_rne(float f){
    union{float f; uint u;} x; x.f=f;
    uint r = (x.u + 0x7FFFu + ((x.u>>16)&1u)) >> 16;
    return (ushort)r;
}
__device__ __forceinline__ float bf2f(ushort h){
    union{uint u; float f;} y; y.u = ((uint)h)<<16;
    return y.f;
}

__global__ void init_slast_k(float* __restrict__ s_last){
    int i = blockIdx.x*256 + threadIdx.x;
    s_last[i] = 0.5f;   // sigmoid(0)
}

// convert f32 weights -> bf16 (hi only; 2-product scheme)
__global__ void conv_wh_k(const float* __restrict__ W, ushort* __restrict__ Wh, int n4){
    int i = blockIdx.x*256 + threadIdx.x;
    if(i>=n4) return;
    float4 v = ((const float4*)W)[i];
    ushort4 hv;
    hv.x=f2bf_rne(v.x); hv.y=f2bf_rne(v.y); hv.z=f2bf_rne(v.z); hv.w=f2bf_rne(v.w);
    ((ushort4*)Wh)[i] = hv;
}

// W_ih_dec [1536][128] f32 -> transposed bf16 WT[128][1536]
__global__ void conv_widT_k(const float* __restrict__ W, ushort* __restrict__ WT){
    int i = blockIdx.x*256 + threadIdx.x;     // over 128*1536
    if(i >= 128*1536) return;
    int k = i / 1536, n = i % 1536;
    WT[i] = f2bf_rne(W[n*128 + k]);
}

// ---- swizzled async staging: 64 rows x 64 bf16 cols -> 8KB LDS (linear dest,
//      pre-swizzled global source; element (r,c) @ LDS r*128 + ((c>>3)^(r&7))*16 + (c&7)*2 )
__device__ __forceinline__ void stage_swz(const ushort* __restrict__ g, int K,
        int grow0, int kb, ushort* lds, int tid){
    int wv = tid>>6, lane = tid&63;
    #pragma unroll
    for(int q=0;q<2;q++){
        int instr = wv*2 + q;
        int rl = instr*8 + (lane>>3);
        int sc = (lane&7) ^ (lane>>3);
        const ushort* src = g + (size_t)(grow0+rl)*K + kb + sc*8;
        ushort* dst = lds + instr*512;     // wave-uniform; HW adds lane*16 bytes
        __builtin_amdgcn_global_load_lds((const __attribute__((address_space(1))) void*)src,
                                         (__attribute__((address_space(3))) void*)dst, 16, 0, 0);
    }
}

// read 8 bf16 at (row r, slot 0..7) from one swizzled 64x64 LDS subtile
__device__ __forceinline__ short8 lds_read_swz(const ushort* arr, int r, int slot){
    return *(const short8*)&arr[r*64 + ((slot ^ (r&7))<<3)];
}

// read across BK=128 buffer (2 subtiles): slot16 in 0..15
__device__ __forceinline__ short8 lds_read_swz128(const ushort* arr, int r, int slot16){
    return lds_read_swz(arr + (slot16>>3)*4096, r, slot16&7);
}

// ---- attention params with NT=512 threads ----
__device__ __forceinline__ void attn_params_dev512(const float* __restrict__ h,
        const float* __restrict__ W, const float* __restrict__ bvec,
        float* red5, float* pp, int tid){
    float accp[5];
    #pragma unroll
    for(int i=0;i<5;i++) accp[i]=0.f;
    for(int k=tid;k<HDIM;k+=512){
        float hv = h[k];
        #pragma unroll
        for(int i=0;i<5;i++) accp[i] += hv*W[i*HDIM+k];
    }
    int wv = tid>>6;
    #pragma unroll
    for(int i=0;i<5;i++){
        float a = accp[i];
        #pragma unroll
        for(int o=32;o>0;o>>=1) a += __shfl_down(a,o);
        if((tid&63)==0) red5[i*8+wv]=a;
    }
    __syncthreads();
    if(tid<5){
        float s = bvec[tid];
        #pragma unroll
        for(int w2=0;w2<8;w2++) s += red5[tid*8+w2];
        pp[tid]=s;
    }
    __syncthreads();
}

// transposed fill: fxT[pix][j], fyT[pix][j]; NT=512
__device__ __forceinline__ void fill_fb_T(float* fxT, float* fyT, const float* pp, int tid){
    float gx = 64.5f*(pp[0]+1.0f);
    float gy = 64.5f*(pp[1]+1.0f);
    float tss = 2.0f*expf(pp[2]);
    float delta = (127.0f/31.0f)*expf(pp[3]);
    int rr = tid>>3;
    int q  = tid&7;
    int j  = rr&31;
    bool isY = rr>=32;
    float mu = (isY?gy:gx) + ((float)j-15.5f)*delta;
    float v[16]; float s=0.f;
    #pragma unroll
    for(int i=0;i<16;i++){
        float d = (float)(q*16+i)-mu;
        float e = expf(-d*d/tss);
        v[i]=e; s+=e;
    }
    s += __shfl_xor(s,1); s += __shfl_xor(s,2); s += __shfl_xor(s,4);
    float inv = 1.0f/fmaxf(s,1e-8f);
    float* dst = isY? fyT : fxT;
    #pragma unroll
    for(int i=0;i<16;i++) dst[(q*16+i)*32 + j] = v[i]*inv;
    __syncthreads();
}

// row-major fill: fx[32][129], fy[32][129]; NT=512
__device__ __forceinline__ void fill_fb_R(float (*fx)[ABDIM+1], float (*fy)[ABDIM+1], const float* pp, int tid){
    float gx = 64.5f*(pp[0]+1.0f);
    float gy = 64.5f*(pp[1]+1.0f);
    float tss = 2.0f*expf(pp[2]);
    float delta = (127.0f/31.0f)*expf(pp[3]);
    int rr = tid>>3;
    int q  = tid&7;
    int j  = rr&31;
    bool isY = rr>=32;
    float mu = (isY?gy:gx) + ((float)j-15.5f)*delta;
    float v[16]; float s=0.f;
    #pragma unroll
    for(int i=0;i<16;i++){
        float d = (float)(q*16+i)-mu;
        float e = expf(-d*d/tss);
        v[i]=e; s+=e;
    }
    s += __shfl_xor(s,1); s += __shfl_xor(s,2); s += __shfl_xor(s,4);
    float inv = 1.0f/fmaxf(s,1e-8f);
    float* rowp = isY? &fy[j][0] : &fx[j][0];
    #pragma unroll
    for(int i=0;i<16;i++) rowp[q*16+i] = v[i]*inv;
    __syncthreads();
}

// per-batch fused read attention; 512 threads; 2 blocks per batch (split by j half)
__global__ __launch_bounds__(512) void read_attn_k(const float* __restrict__ xf, const float* __restrict__ s_last,
        const float* __restrict__ hdec, const ushort* __restrict__ Hd_h, const ushort* __restrict__ Hd_l,
        const float* __restrict__ W_ra, const float* __restrict__ b_ra,
        ushort* __restrict__ Eh, ushort* __restrict__ El){
    __shared__ float smem[4096 + 8256 + 48];
    float* sFxT = smem;                   // [128][32]
    float* sFyT = smem + 4096;            // [128][32]
    float* tmp  = smem + 4096;            // aliases sFyT: [2][16][129]
    float* red5 = smem + 4096 + 8256;
    float* pp   = red5 + 40;
    int bb = blockIdx.x >> 1, half = blockIdx.x & 1;
    int tid = threadIdx.x;
    const float* h = hdec + bb*HDIM;
    attn_params_dev512(h, W_ra, b_ra, red5, pp, tid);
    float gamma = expf(pp[4]);
    fill_fb_T(sFxT, sFyT, pp, tid);

    const float* img = xf + (size_t)bb*IMGSZ;
    int c = tid & 127;
    int jg = tid >> 7;                    // 0..3: 4 j's each
    int jbase = half*16 + jg*4;
    float acc0[4], accS[4];
    #pragma unroll
    for(int i=0;i<4;i++){ acc0[i]=0.f; accS[i]=0.f; }
    for(int k=0;k<ABDIM;k++){
        float s  = img[k*ABDIM + c];
        float sl = s_last[k*ABDIM + c];
        float4 f0 = *(const float4*)&sFyT[k*32 + jbase];
        acc0[0]+=f0.x*s;  acc0[1]+=f0.y*s;  acc0[2]+=f0.z*s;  acc0[3]+=f0.w*s;
        accS[0]+=f0.x*sl; accS[1]+=f0.y*sl; accS[2]+=f0.z*sl; accS[3]+=f0.w*sl;
    }
    __syncthreads();                      // done reading sFyT
    #pragma unroll
    for(int i=0;i<4;i++){
        int jl = jg*4+i;                  // local j index 0..15
        tmp[0*16*129 + jl*129 + c] = acc0[i];
        tmp[1*16*129 + jl*129 + c] = acc0[i] - accS[i];
    }
    __syncthreads();
    {
        int i2 = tid & 15;
        int jl = (tid>>4) & 15;
        int p  = tid >> 8;
        float a0=0.f, a1=0.f;
        for(int cc=0; cc<ABDIM; cc++){
            float tv = tmp[p*16*129 + jl*129 + cc];
            a0 += tv*sFxT[cc*32 + i2*2];
            a1 += tv*sFxT[cc*32 + i2*2 + 1];
        }
        float o0 = gamma*a0, o1 = gamma*a1;
        int j = half*16 + jl;
        ushort h0=f2bf_rne(o0), h1=f2bf_rne(o1);
        ushort2 oh; oh.x=h0; oh.y=h1;
        ushort2 ol; ol.x=f2bf_rne(o0-bf2f(h0)); ol.y=f2bf_rne(o1-bf2f(h1));
        size_t off = (size_t)bb*ENCIN + p*1024 + j*NGRID + i2*2;
        *(ushort2*)(Eh + off) = oh;
        *(ushort2*)(El + off) = ol;
    }
    if(half==0){
        int i = tid;
        Eh[(size_t)bb*ENCIN + 2048 + i] = Hd_h[(size_t)bb*HDIM + i];
        El[(size_t)bb*ENCIN + 2048 + i] = Hd_l[(size_t)bb*HDIM + i];
    }
}

// ---- one MFMA GEMM tile (2-product split-bf16), 64x64, 256thr, BK=128, gload_lds+swizzle ----
__device__ void gemm_one(const ushort* __restrict__ Agh, const ushort* __restrict__ Agl,
        const ushort* __restrict__ Wh,
        int K, int k0, int kiters, int row0, int col0, int Nn, float* __restrict__ Out,
        ushort* AH, ushort* AL, ushort* BH, int tid){
    int lane = tid&63, w = tid>>6;
    int m0 = (w>>1)*32, n0 = (w&1)*32;
    int fr = lane&15, sl = lane>>4;
    f32x4 acc[2][2];
    #pragma unroll
    for(int i=0;i<2;i++)
        #pragma unroll
        for(int j=0;j<2;j++) acc[i][j]=(f32x4){0.f,0.f,0.f,0.f};
    for(int it=0; it<kiters; ++it){
        int kb = k0 + it*128;
        stage_swz(Agh, K, row0, kb,    AH,      tid);
        stage_swz(Agh, K, row0, kb+64, AH+4096, tid);
        stage_swz(Agl, K, row0, kb,    AL,      tid);
        stage_swz(Agl, K, row0, kb+64, AL+4096, tid);
        stage_swz(Wh,  K, col0, kb,    BH,      tid);
        stage_swz(Wh,  K, col0, kb+64, BH+4096, tid);
        __syncthreads();                    // vmcnt(0) drain + barrier
        #pragma unroll
        for(int ks=0; ks<4; ks++){
            int slot = ks*4 + sl;           // 0..15 across 128 K
            short8 a_h[2], a_l[2], b_h[2];
            #pragma unroll
            for(int mf=0;mf<2;mf++){
                a_h[mf] = lds_read_swz128(AH, m0+mf*16+fr, slot);
                a_l[mf] = lds_read_swz128(AL, m0+mf*16+fr, slot);
            }
            #pragma unroll
            for(int nf=0;nf<2;nf++)
                b_h[nf] = lds_read_swz128(BH, n0+nf*16+fr, slot);
            #pragma unroll
            for(int mf=0;mf<2;mf++)
                #pragma unroll
                for(int nf=0;nf<2;nf++){
                    acc[mf][nf] = __builtin_amdgcn_mfma_f32_16x16x32_bf16(a_h[mf], b_h[nf], acc[mf][nf], 0,0,0);
                    acc[mf][nf] = __builtin_amdgcn_mfma_f32_16x16x32_bf16(a_l[mf], b_h[nf], acc[mf][nf], 0,0,0);
                }
        }
        __syncthreads();                    // readers done before next iter's writes
    }
    int crow = (lane>>4)*4, ccol = lane&15;
    #pragma unroll
    for(int mf=0;mf<2;mf++)
        #pragma unroll
        for(int nf=0;nf<2;nf++)
            #pragma unroll
            for(int r=0;r<4;r++)
                Out[(size_t)(row0+m0+mf*16+crow+r)*Nn + col0+n0+nf*16+ccol] = acc[mf][nf][r];
}

// job pool: enc-i splitk4 (384 jobs @5 it) + enc-h (96 @4) + dec-h (96 @4) = 576 blocks
__global__ __launch_bounds__(256) void gemm3_k(
        const ushort* __restrict__ Eh, const ushort* __restrict__ El,
        const ushort* __restrict__ Wie_h,
        const ushort* __restrict__ He_h, const ushort* __restrict__ He_l,
        const ushort* __restrict__ Whe_h,
        const ushort* __restrict__ Hd_h, const ushort* __restrict__ Hd_l,
        const ushort* __restrict__ Whd_h,
        float* __restrict__ Pi, float* __restrict__ Ph, float* __restrict__ Ph2){
    __shared__ ushort AH[2*64*64], AL[2*64*64], BH[2*64*64];
    int job = blockIdx.x, tid = threadIdx.x;
    if(job < 384){
        int tile = job % 96, s = job / 96;
        gemm_one(Eh, El, Wie_h, ENCIN, s*640, 5,
                 (tile/24)*64, (tile%24)*64, G3, Pi + (size_t)s*SLAB, AH, AL, BH, tid);
    } else if(job < 480){
        int tile = job - 384;
        gemm_one(He_h, He_l, Whe_h, HDIM, 0, 4,
                 (tile/24)*64, (tile%24)*64, G3, Ph, AH, AL, BH, tid);
    } else {
        int tile = job - 480;
        gemm_one(Hd_h, Hd_l, Whd_h, HDIM, 0, 4,
                 (tile/24)*64, (tile%24)*64, G3, Ph2, AH, AL, BH, tid);
    }
}

// write GEMM: grid (16 cols, 4 rows, 2 splits), 64x64 tiles, K=512
__global__ __launch_bounds__(256) void gemm_wr_k(
        const ushort* __restrict__ Hd_h, const ushort* __restrict__ Hd_l,
        const ushort* __restrict__ Wwr_h,
        float* __restrict__ Pw){
    __shared__ ushort AH[2*64*64], AL[2*64*64], BH[2*64*64];
    int tid = threadIdx.x;
    int r0 = blockIdx.y*64, c0 = blockIdx.x*64, s = blockIdx.z;
    gemm_one(Hd_h, Hd_l, Wwr_h, HDIM, s*256, 2, r0, c0, 1024,
             Pw + (size_t)s*BATCHN*1024, AH, AL, BH, tid);
}

// merged: encoder combine (4 Pi + 1 Ph) -> h_enc/mirrors; z sample -> LDS;
//         dec-i GEMV (f32 Z x bf16 WidT, coalesced) + decoder combine -> h_dec/mirrors
__global__ __launch_bounds__(512) void combine_all_k(const float* __restrict__ Pi, const float* __restrict__ Ph,
        const float* __restrict__ bie, const float* __restrict__ bhe,
        float* __restrict__ h_enc, ushort* __restrict__ Heh, ushort* __restrict__ Hel,
        const float* __restrict__ Wmu, const float* __restrict__ bmu,
        const float* __restrict__ Wls, const float* __restrict__ bls,
        const float* __restrict__ eps_t,
        const ushort* __restrict__ WidT, const float* __restrict__ Ph2,
        const float* __restrict__ bid_, const float* __restrict__ bhd,
        float* __restrict__ h_dec, ushort* __restrict__ Hdh, ushort* __restrict__ Hdl){
    __shared__ float hs[HDIM];
    __shared__ float zs[ZDIM];
    int bb = blockIdx.x, tid = threadIdx.x;
    // ---- encoder combine ----
    {
        int j = tid;
        float gi_r=bie[j], gi_z=bie[512+j], gi_n=bie[1024+j];
        float gh_r=bhe[j], gh_z=bhe[512+j], gh_n=bhe[1024+j];
        #pragma unroll
        for(int s=0;s<4;s++){
            size_t base = (size_t)s*SLAB + (size_t)bb*G3 + j;
            gi_r += Pi[base]; gi_z += Pi[base+512]; gi_n += Pi[base+1024];
        }
        {
            size_t base = (size_t)bb*G3 + j;
            gh_r += Ph[base]; gh_z += Ph[base+512]; gh_n += Ph[base+1024];
        }
        float r = sigmoidf_(gi_r + gh_r);
        float z = sigmoidf_(gi_z + gh_z);
        float n = tanhf(gi_n + r*gh_n);
        size_t hoff = (size_t)bb*HDIM + j;
        float hn = (1.f - z)*n + z*h_enc[hoff];
        h_enc[hoff] = hn; hs[j] = hn;
        ushort hh = f2bf_rne(hn);
        Heh[hoff] = hh; Hel[hoff] = f2bf_rne(hn - bf2f(hh));
    }
    __syncthreads();
    // ---- z sample: wave per output; coalesced weight rows ----
    {
        int wv = tid>>6, lane = tid&63;
        const float4* hs4 = (const float4*)hs;
        float4 h0 = hs4[lane*2];
        float4 h1 = hs4[lane*2+1];
        #pragma unroll 4
        for(int it=0; it<16; ++it){
            int jo = wv*16 + it;
            const float4* wm = (const float4*)(Wmu + (size_t)jo*HDIM);
            const float4* wl = (const float4*)(Wls + (size_t)jo*HDIM);
            float4 m0=wm[lane*2], m1=wm[lane*2+1];
            float4 l0=wl[lane*2], l1=wl[lane*2+1];
            float am  = h0.x*m0.x+h0.y*m0.y+h0.z*m0.z+h0.w*m0.w
                      + h1.x*m1.x+h1.y*m1.y+h1.z*m1.z+h1.w*m1.w;
            float al_ = h0.x*l0.x+h0.y*l0.y+h0.z*l0.z+h0.w*l0.w
                      + h1.x*l1.x+h1.y*l1.y+h1.z*l1.z+h1.w*l1.w;
            #pragma unroll
            for(int o=32;o>0;o>>=1){ am += __shfl_down(am,o); al_ += __shfl_down(al_,o); }
            if(lane==0){
                float mu = am + bmu[jo];
                float sg = expf(al_ + bls[jo]);
                zs[jo] = mu + eps_t[(size_t)bb*ZDIM + jo]*sg;
            }
        }
    }
    __syncthreads();
    // ---- dec-i GEMV + decoder combine: thread nn owns gates at cols nn/+512/+1024 ----
    {
        int nn = tid;
        float gr=0.f, gz=0.f, gn=0.f;
        #pragma unroll 4
        for(int k=0;k<ZDIM;k++){
            float zk = zs[k];
            const ushort* wrow = WidT + (size_t)k*G3;
            gr += zk*bf2f(wrow[nn]);
            gz += zk*bf2f(wrow[512+nn]);
            gn += zk*bf2f(wrow[1024+nn]);
        }
        size_t base = (size_t)bb*G3 + nn;
        float gi_r = gr + bid_[nn];
        float gi_z = gz + bid_[512+nn];
        float gi_n = gn + bid_[1024+nn];
        float gh_r = Ph2[base]      + bhd[nn];
        float gh_z = Ph2[base+512]  + bhd[512+nn];
        float gh_n = Ph2[base+1024] + bhd[1024+nn];
        float rr = sigmoidf_(gi_r + gh_r);
        float zz = sigmoidf_(gi_z + gh_z);
        float nv = tanhf(gi_n + rr*gh_n);
        size_t idx = (size_t)bb*HDIM + nn;
        float hn = (1.f - zz)*nv + zz*h_dec[idx];
        h_dec[idx] = hn;
        ushort hh = f2bf_rne(hn);
        Hdh[idx] = hh; Hdl[idx] = f2bf_rne(hn - bf2f(hh));
    }
}

// write path: 2 blocks per batch (split by rec row half); reduce(Pw,2 slabs)+apply
// last!=0: apply final sigmoid to rec
__global__ __launch_bounds__(512) void write_apply_k(const float* __restrict__ Pw, const float* __restrict__ b_wr,
        const float* __restrict__ hdec, const float* __restrict__ W_wa, const float* __restrict__ b_wa,
        float* __restrict__ rec, float* __restrict__ s_last, int last){
    __shared__ float sFy[NGRID][ABDIM+1];
    __shared__ float sFx[NGRID][ABDIM+1];
    __shared__ float sw[NGRID][36];
    __shared__ float t[64][36];
    __shared__ float red5[40];
    __shared__ float pp[8];
    int bb = blockIdx.x >> 1, half = blockIdx.x & 1;
    int p0 = half*64;
    int tid = threadIdx.x;
    const float* h = hdec + bb*HDIM;
    attn_params_dev512(h, W_wa, b_wa, red5, pp, tid);
    float invg = expf(-pp[4]);
    fill_fb_R(sFx, sFy, pp, tid);
    for(int i=tid;i<NGRID*NGRID;i+=512){
        float a = b_wr[i];
        #pragma unroll
        for(int s=0;s<2;s++) a += Pw[((size_t)s*BATCHN + bb)*1024 + i];
        sw[i>>5][i&31] = a;
    }
    __syncthreads();
    {
        int pl = tid>>3, iq = tid&7;
        int p = p0 + pl;
        float a[4];
        #pragma unroll
        for(int i=0;i<4;i++) a[i]=0.f;
        for(int j=0;j<NGRID;j++){
            float fy = sFy[j][p];
            float4 w0 = *(const float4*)&sw[j][iq*4];
            a[0]+=fy*w0.x; a[1]+=fy*w0.y; a[2]+=fy*w0.z; a[3]+=fy*w0.w;
        }
        float4 o0; o0.x=a[0];o0.y=a[1];o0.z=a[2];o0.w=a[3];
        *(float4*)&t[pl][iq*4] = o0;
    }
    __syncthreads();
    {
        int q = tid&127, pg = tid>>7;
        float fxc[32];
        #pragma unroll
        for(int i=0;i<32;i++) fxc[i] = sFx[i][q];
        for(int pi=0; pi<16; pi++){
            int pl = pg*16 + pi;
            int p = p0 + pl;
            float acc = 0.f;
            #pragma unroll
            for(int i4=0;i4<8;i4++){
                float4 tv = *(const float4*)&t[pl][i4*4];
                acc += tv.x*fxc[i4*4] + tv.y*fxc[i4*4+1] + tv.z*fxc[i4*4+2] + tv.w*fxc[i4*4+3];
            }
            size_t off = (size_t)bb*IMGSZ + p*ABDIM + q;
            float nv = rec[off] + acc*invg;
            rec[off] = last ? sigmoidf_(nv) : nv;
            if(bb==BATCHN-1) s_last[p*ABDIM + q] = sigmoidf_(nv);
        }
    }
}

extern "C" void kernel_launch(void* const* d_in, const int* in_sizes, int n_in,
                              void* d_out, int out_size, void* d_ws, size_t ws_size,
                              hipStream_t stream) {
    const float* x        = (const float*)d_in[0];
    const float* eps      = (const float*)d_in[1];
    const float* W_ih_enc = (const float*)d_in[2];
    const float* W_hh_enc = (const float*)d_in[3];
    const float* b_ih_enc = (const float*)d_in[4];
    const float* b_hh_enc = (const float*)d_in[5];
    const float* W_ih_dec = (const float*)d_in[6];
    const float* W_hh_dec = (const float*)d_in[7];
    const float* b_ih_dec = (const float*)d_in[8];
    const float* b_hh_dec = (const float*)d_in[9];
    const float* W_mu     = (const float*)d_in[10];
    const float* b_mu     = (const float*)d_in[11];
    const float* W_ls     = (const float*)d_in[12];
    const float* b_ls     = (const float*)d_in[13];
    const float* W_wr     = (const float*)d_in[14];
    const float* b_wr     = (const float*)d_in[15];
    const float* W_ra     = (const float*)d_in[16];
    const float* b_ra     = (const float*)d_in[17];
    const float* W_wa     = (const float*)d_in[18];
    const float* b_wa     = (const float*)d_in[19];

    float* rec = (float*)d_out;

    float* ws = (float*)d_ws;
    float* h_enc  = ws;  ws += BATCHN*HDIM;
    float* h_dec  = ws;  ws += BATCHN*HDIM;
    float* s_last = ws;  ws += IMGSZ;
    float* Pi     = ws;  ws += (size_t)4*SLAB;
    float* Ph     = ws;  ws += (size_t)SLAB;
    float* Ph2    = ws;  ws += (size_t)SLAB;
    float* Pw     = ws;  ws += (size_t)2*BATCHN*1024;

    ushort* us = (ushort*)ws;
    ushort* Wie_h = us; us += 1536*2560;
    ushort* Whe_h = us; us += 1536*512;
    ushort* Whd_h = us; us += 1536*512;
    ushort* WidT  = us; us += 128*1536;
    ushort* Wwr_h = us; us += 1024*512;
    ushort* Eh    = us; us += BATCHN*ENCIN;
    ushort* El    = us; us += BATCHN*ENCIN;
    ushort* He_h  = us; us += BATCHN*HDIM;
    ushort* He_l  = us; us += BATCHN*HDIM;
    ushort* Hd_h  = us; us += BATCHN*HDIM;
    ushort* Hd_l  = us; us += BATCHN*HDIM;

    hipMemsetAsync(rec,   0, (size_t)BATCHN*IMGSZ*sizeof(float), stream);
    hipMemsetAsync(h_enc, 0, (size_t)BATCHN*HDIM*sizeof(float), stream);
    hipMemsetAsync(h_dec, 0, (size_t)BATCHN*HDIM*sizeof(float), stream);
    hipMemsetAsync(He_h,  0, (size_t)BATCHN*HDIM*sizeof(ushort)*2, stream);  // He_h+He_l contiguous
    hipMemsetAsync(Hd_h,  0, (size_t)BATCHN*HDIM*sizeof(ushort)*2, stream);  // Hd_h+Hd_l contiguous
    init_slast_k<<<IMGSZ/256,256,0,stream>>>(s_last);

    conv_wh_k<<<(1536*2560/4+255)/256,256,0,stream>>>(W_ih_enc, Wie_h, 1536*2560/4);
    conv_wh_k<<<(1536*512/4+255)/256,256,0,stream>>>(W_hh_enc, Whe_h, 1536*512/4);
    conv_wh_k<<<(1536*512/4+255)/256,256,0,stream>>>(W_hh_dec, Whd_h, 1536*512/4);
    conv_widT_k<<<(128*1536+255)/256,256,0,stream>>>(W_ih_dec, WidT);
    conv_wh_k<<<(1024*512/4+255)/256,256,0,stream>>>(W_wr, Wwr_h, 1024*512/4);

    for(int t=0;t<16;t++){
        read_attn_k<<<2*BATCHN,512,0,stream>>>(x, s_last, h_dec, Hd_h, Hd_l, W_ra, b_ra, Eh, El);
        gemm3_k<<<576,256,0,stream>>>(Eh, El, Wie_h, He_h, He_l, Whe_h,
                                      Hd_h, Hd_l, Whd_h, Pi, Ph, Ph2);
        combine_all_k<<<BATCHN,512,0,stream>>>(Pi, Ph, b_ih_enc, b_hh_enc,
            h_enc, He_h, He_l, W_mu, b_mu, W_ls, b_ls, eps + (size_t)t*BATCHN*ZDIM,
            WidT, Ph2, b_ih_dec, b_hh_dec, h_dec, Hd_h, Hd_l);
        gemm_wr_k<<<dim3(16,4,2),256,0,stream>>>(Hd_h, Hd_l, Wwr_h, Pw);
        write_apply_k<<<2*BATCHN,512,0,stream>>>(Pw, b_wr, h_dec, W_wa, b_wa, rec, s_last,
                                                 (t==15)?1:0);
    }
}

// Round 14
// 1359.641 us; speedup vs baseline: 1.0274x; 1.0274x over previous
//
#include <hip/hip_runtime.h>
#include <math.h>

#define BATCHN 256
#define HDIM 512
#define ZDIM 128
#define NGRID 32
#define ABDIM 128
#define IMGSZ 16384   // 128*128
#define ENCIN 2560
#define G3 1536
#define SLAB (BATCHN*G3)

typedef __attribute__((ext_vector_type(8))) short short8;
typedef __attribute__((ext_vector_type(4))) float f32x4;

__device__ __forceinline__ float sigmoidf_(float x){ return 1.0f/(1.0f+expf(-x)); }

__device__ __forceinline__ ushort f2bf_rne(float f){
    union{float f; uint u;} x; x.f=f;
    uint r = (x.u + 0x7FFFu + ((x.u>>16)&1u)) >> 16;
    return (ushort)r;
}
__device__ __forceinline__ float bf2f(ushort h){
    union{uint u; float f;} y; y.u = ((uint)h)<<16;
    return y.f;
}

__global__ void init_slast_k(float* __restrict__ s_last){
    int i = blockIdx.x*256 + threadIdx.x;
    s_last[i] = 0.5f;   // sigmoid(0)
}

// convert f32 weights -> bf16 (hi only; 2-product scheme)
__global__ void conv_wh_k(const float* __restrict__ W, ushort* __restrict__ Wh, int n4){
    int i = blockIdx.x*256 + threadIdx.x;
    if(i>=n4) return;
    float4 v = ((const float4*)W)[i];
    ushort4 hv;
    hv.x=f2bf_rne(v.x); hv.y=f2bf_rne(v.y); hv.z=f2bf_rne(v.z); hv.w=f2bf_rne(v.w);
    ((ushort4*)Wh)[i] = hv;
}

// ---- swizzled async staging: 64 rows x 64 bf16 cols -> 8KB LDS (linear dest,
//      pre-swizzled global source; element (r,c) @ LDS r*128 + ((c>>3)^(r&7))*16 + (c&7)*2 )
__device__ __forceinline__ void stage_swz(const ushort* __restrict__ g, int K,
        int grow0, int kb, ushort* lds, int tid){
    int wv = tid>>6, lane = tid&63;
    #pragma unroll
    for(int q=0;q<2;q++){
        int instr = wv*2 + q;
        int rl = instr*8 + (lane>>3);
        int sc = (lane&7) ^ (lane>>3);
        const ushort* src = g + (size_t)(grow0+rl)*K + kb + sc*8;
        ushort* dst = lds + instr*512;     // wave-uniform; HW adds lane*16 bytes
        __builtin_amdgcn_global_load_lds((const __attribute__((address_space(1))) void*)src,
                                         (__attribute__((address_space(3))) void*)dst, 16, 0, 0);
    }
}

// read 8 bf16 at (row r, slot 0..7) from one swizzled 64x64 LDS subtile
__device__ __forceinline__ short8 lds_read_swz(const ushort* arr, int r, int slot){
    return *(const short8*)&arr[r*64 + ((slot ^ (r&7))<<3)];
}

// read across BK=128 buffer (2 subtiles): slot16 in 0..15
__device__ __forceinline__ short8 lds_read_swz128(const ushort* arr, int r, int slot16){
    return lds_read_swz(arr + (slot16>>3)*4096, r, slot16&7);
}

// ---- attention params with NT=512 threads ----
__device__ __forceinline__ void attn_params_dev512(const float* __restrict__ h,
        const float* __restrict__ W, const float* __restrict__ bvec,
        float* red5, float* pp, int tid){
    float accp[5];
    #pragma unroll
    for(int i=0;i<5;i++) accp[i]=0.f;
    for(int k=tid;k<HDIM;k+=512){
        float hv = h[k];
        #pragma unroll
        for(int i=0;i<5;i++) accp[i] += hv*W[i*HDIM+k];
    }
    int wv = tid>>6;
    #pragma unroll
    for(int i=0;i<5;i++){
        float a = accp[i];
        #pragma unroll
        for(int o=32;o>0;o>>=1) a += __shfl_down(a,o);
        if((tid&63)==0) red5[i*8+wv]=a;
    }
    __syncthreads();
    if(tid<5){
        float s = bvec[tid];
        #pragma unroll
        for(int w2=0;w2<8;w2++) s += red5[tid*8+w2];
        pp[tid]=s;
    }
    __syncthreads();
}

// transposed fill: fxT[pix][j], fyT[pix][j]; NT=512
__device__ __forceinline__ void fill_fb_T(float* fxT, float* fyT, const float* pp, int tid){
    float gx = 64.5f*(pp[0]+1.0f);
    float gy = 64.5f*(pp[1]+1.0f);
    float tss = 2.0f*expf(pp[2]);
    float delta = (127.0f/31.0f)*expf(pp[3]);
    int rr = tid>>3;
    int q  = tid&7;
    int j  = rr&31;
    bool isY = rr>=32;
    float mu = (isY?gy:gx) + ((float)j-15.5f)*delta;
    float v[16]; float s=0.f;
    #pragma unroll
    for(int i=0;i<16;i++){
        float d = (float)(q*16+i)-mu;
        float e = expf(-d*d/tss);
        v[i]=e; s+=e;
    }
    s += __shfl_xor(s,1); s += __shfl_xor(s,2); s += __shfl_xor(s,4);
    float inv = 1.0f/fmaxf(s,1e-8f);
    float* dst = isY? fyT : fxT;
    #pragma unroll
    for(int i=0;i<16;i++) dst[(q*16+i)*32 + j] = v[i]*inv;
    __syncthreads();
}

// row-major fill: fx[32][129], fy[32][129]; NT=512
__device__ __forceinline__ void fill_fb_R(float (*fx)[ABDIM+1], float (*fy)[ABDIM+1], const float* pp, int tid){
    float gx = 64.5f*(pp[0]+1.0f);
    float gy = 64.5f*(pp[1]+1.0f);
    float tss = 2.0f*expf(pp[2]);
    float delta = (127.0f/31.0f)*expf(pp[3]);
    int rr = tid>>3;
    int q  = tid&7;
    int j  = rr&31;
    bool isY = rr>=32;
    float mu = (isY?gy:gx) + ((float)j-15.5f)*delta;
    float v[16]; float s=0.f;
    #pragma unroll
    for(int i=0;i<16;i++){
        float d = (float)(q*16+i)-mu;
        float e = expf(-d*d/tss);
        v[i]=e; s+=e;
    }
    s += __shfl_xor(s,1); s += __shfl_xor(s,2); s += __shfl_xor(s,4);
    float inv = 1.0f/fmaxf(s,1e-8f);
    float* rowp = isY? &fy[j][0] : &fx[j][0];
    #pragma unroll
    for(int i=0;i<16;i++) rowp[q*16+i] = v[i]*inv;
    __syncthreads();
}

// per-batch fused read attention; 512 threads; 2 blocks per batch (split by j half)
__global__ __launch_bounds__(512) void read_attn_k(const float* __restrict__ xf, const float* __restrict__ s_last,
        const float* __restrict__ hdec, const ushort* __restrict__ Hd_h, const ushort* __restrict__ Hd_l,
        const float* __restrict__ W_ra, const float* __restrict__ b_ra,
        ushort* __restrict__ Eh, ushort* __restrict__ El){
    __shared__ float smem[4096 + 8256 + 48];
    float* sFxT = smem;                   // [128][32]
    float* sFyT = smem + 4096;            // [128][32]
    float* tmp  = smem + 4096;            // aliases sFyT: [2][16][129]
    float* red5 = smem + 4096 + 8256;
    float* pp   = red5 + 40;
    int bb = blockIdx.x >> 1, half = blockIdx.x & 1;
    int tid = threadIdx.x;
    const float* h = hdec + bb*HDIM;
    attn_params_dev512(h, W_ra, b_ra, red5, pp, tid);
    float gamma = expf(pp[4]);
    fill_fb_T(sFxT, sFyT, pp, tid);

    const float* img = xf + (size_t)bb*IMGSZ;
    int c = tid & 127;
    int jg = tid >> 7;                    // 0..3: 4 j's each
    int jbase = half*16 + jg*4;
    float acc0[4], accS[4];
    #pragma unroll
    for(int i=0;i<4;i++){ acc0[i]=0.f; accS[i]=0.f; }
    for(int k=0;k<ABDIM;k++){
        float s  = img[k*ABDIM + c];
        float sl = s_last[k*ABDIM + c];
        float4 f0 = *(const float4*)&sFyT[k*32 + jbase];
        acc0[0]+=f0.x*s;  acc0[1]+=f0.y*s;  acc0[2]+=f0.z*s;  acc0[3]+=f0.w*s;
        accS[0]+=f0.x*sl; accS[1]+=f0.y*sl; accS[2]+=f0.z*sl; accS[3]+=f0.w*sl;
    }
    __syncthreads();                      // done reading sFyT
    #pragma unroll
    for(int i=0;i<4;i++){
        int jl = jg*4+i;                  // local j index 0..15
        tmp[0*16*129 + jl*129 + c] = acc0[i];
        tmp[1*16*129 + jl*129 + c] = acc0[i] - accS[i];
    }
    __syncthreads();
    {
        int i2 = tid & 15;
        int jl = (tid>>4) & 15;
        int p  = tid >> 8;
        float a0=0.f, a1=0.f;
        for(int cc=0; cc<ABDIM; cc++){
            float tv = tmp[p*16*129 + jl*129 + cc];
            a0 += tv*sFxT[cc*32 + i2*2];
            a1 += tv*sFxT[cc*32 + i2*2 + 1];
        }
        float o0 = gamma*a0, o1 = gamma*a1;
        int j = half*16 + jl;
        ushort h0=f2bf_rne(o0), h1=f2bf_rne(o1);
        ushort2 oh; oh.x=h0; oh.y=h1;
        ushort2 ol; ol.x=f2bf_rne(o0-bf2f(h0)); ol.y=f2bf_rne(o1-bf2f(h1));
        size_t off = (size_t)bb*ENCIN + p*1024 + j*NGRID + i2*2;
        *(ushort2*)(Eh + off) = oh;
        *(ushort2*)(El + off) = ol;
    }
    if(half==0){
        int i = tid;
        Eh[(size_t)bb*ENCIN + 2048 + i] = Hd_h[(size_t)bb*HDIM + i];
        El[(size_t)bb*ENCIN + 2048 + i] = Hd_l[(size_t)bb*HDIM + i];
    }
}

// ---- one MFMA GEMM tile (2-product split-bf16), 64x64, 256thr, BK=128, gload_lds+swizzle ----
// kiters counts 128-wide K steps; LDS buffers are 2 subtiles of 64x64 (8KB each)
__device__ void gemm_one(const ushort* __restrict__ Agh, const ushort* __restrict__ Agl,
        const ushort* __restrict__ Wh,
        int K, int k0, int kiters, int row0, int col0, int Nn, float* __restrict__ Out,
        ushort* AH, ushort* AL, ushort* BH, int tid){
    int lane = tid&63, w = tid>>6;
    int m0 = (w>>1)*32, n0 = (w&1)*32;
    int fr = lane&15, sl = lane>>4;
    f32x4 acc[2][2];
    #pragma unroll
    for(int i=0;i<2;i++)
        #pragma unroll
        for(int j=0;j<2;j++) acc[i][j]=(f32x4){0.f,0.f,0.f,0.f};
    for(int it=0; it<kiters; ++it){
        int kb = k0 + it*128;
        stage_swz(Agh, K, row0, kb,    AH,      tid);
        stage_swz(Agh, K, row0, kb+64, AH+4096, tid);
        stage_swz(Agl, K, row0, kb,    AL,      tid);
        stage_swz(Agl, K, row0, kb+64, AL+4096, tid);
        stage_swz(Wh,  K, col0, kb,    BH,      tid);
        stage_swz(Wh,  K, col0, kb+64, BH+4096, tid);
        __syncthreads();                    // vmcnt(0) drain + barrier
        #pragma unroll
        for(int ks=0; ks<4; ks++){
            int slot = ks*4 + sl;           // 0..15 across 128 K
            short8 a_h[2], a_l[2], b_h[2];
            #pragma unroll
            for(int mf=0;mf<2;mf++){
                a_h[mf] = lds_read_swz128(AH, m0+mf*16+fr, slot);
                a_l[mf] = lds_read_swz128(AL, m0+mf*16+fr, slot);
            }
            #pragma unroll
            for(int nf=0;nf<2;nf++)
                b_h[nf] = lds_read_swz128(BH, n0+nf*16+fr, slot);
            #pragma unroll
            for(int mf=0;mf<2;mf++)
                #pragma unroll
                for(int nf=0;nf<2;nf++){
                    acc[mf][nf] = __builtin_amdgcn_mfma_f32_16x16x32_bf16(a_h[mf], b_h[nf], acc[mf][nf], 0,0,0);
                    acc[mf][nf] = __builtin_amdgcn_mfma_f32_16x16x32_bf16(a_l[mf], b_h[nf], acc[mf][nf], 0,0,0);
                }
        }
        __syncthreads();                    // readers done before next iter's writes
    }
    int crow = (lane>>4)*4, ccol = lane&15;
    #pragma unroll
    for(int mf=0;mf<2;mf++)
        #pragma unroll
        for(int nf=0;nf<2;nf++)
            #pragma unroll
            for(int r=0;r<4;r++)
                Out[(size_t)(row0+m0+mf*16+crow+r)*Nn + col0+n0+nf*16+ccol] = acc[mf][nf][r];
}

// job pool: enc-i splitk4 (384 jobs @5 it) + enc-h (96 @4) + dec-h (96 @4) = 576 blocks
__global__ __launch_bounds__(256) void gemm3_k(
        const ushort* __restrict__ Eh, const ushort* __restrict__ El,
        const ushort* __restrict__ Wie_h,
        const ushort* __restrict__ He_h, const ushort* __restrict__ He_l,
        const ushort* __restrict__ Whe_h,
        const ushort* __restrict__ Hd_h, const ushort* __restrict__ Hd_l,
        const ushort* __restrict__ Whd_h,
        float* __restrict__ Pi, float* __restrict__ Ph, float* __restrict__ Ph2){
    __shared__ ushort AH[2*64*64], AL[2*64*64], BH[2*64*64];
    int job = blockIdx.x, tid = threadIdx.x;
    if(job < 384){
        int tile = job % 96, s = job / 96;
        gemm_one(Eh, El, Wie_h, ENCIN, s*640, 5,
                 (tile/24)*64, (tile%24)*64, G3, Pi + (size_t)s*SLAB, AH, AL, BH, tid);
    } else if(job < 480){
        int tile = job - 384;
        gemm_one(He_h, He_l, Whe_h, HDIM, 0, 4,
                 (tile/24)*64, (tile%24)*64, G3, Ph, AH, AL, BH, tid);
    } else {
        int tile = job - 480;
        gemm_one(Hd_h, Hd_l, Whd_h, HDIM, 0, 4,
                 (tile/24)*64, (tile%24)*64, G3, Ph2, AH, AL, BH, tid);
    }
}

// write GEMM: grid (16 cols, 4 rows, 2 splits), 64x64 tiles, K=512
__global__ __launch_bounds__(256) void gemm_wr_k(
        const ushort* __restrict__ Hd_h, const ushort* __restrict__ Hd_l,
        const ushort* __restrict__ Wwr_h,
        float* __restrict__ Pw){
    __shared__ ushort AH[2*64*64], AL[2*64*64], BH[2*64*64];
    int tid = threadIdx.x;
    int r0 = blockIdx.y*64, c0 = blockIdx.x*64, s = blockIdx.z;
    gemm_one(Hd_h, Hd_l, Wwr_h, HDIM, s*256, 2, r0, c0, 1024,
             Pw + (size_t)s*BATCHN*1024, AH, AL, BH, tid);
}

// encoder combine (4 Pi + 1 Ph) + z sample -> Zh/Zl mirrors
__global__ __launch_bounds__(512) void combine_z_k(const float* __restrict__ Pi, const float* __restrict__ Ph,
        const float* __restrict__ bi, const float* __restrict__ bh,
        float* __restrict__ h, ushort* __restrict__ Hh, ushort* __restrict__ Hl,
        const float* __restrict__ Wmu, const float* __restrict__ bmu,
        const float* __restrict__ Wls, const float* __restrict__ bls,
        const float* __restrict__ eps_t, ushort* __restrict__ Zh, ushort* __restrict__ Zl){
    __shared__ float hs[HDIM];
    int bb = blockIdx.x, tid = threadIdx.x;
    int j = tid;
    float gi_r=bi[j], gi_z=bi[512+j], gi_n=bi[1024+j];
    float gh_r=bh[j], gh_z=bh[512+j], gh_n=bh[1024+j];
    #pragma unroll
    for(int s=0;s<4;s++){
        size_t base = (size_t)s*SLAB + (size_t)bb*G3 + j;
        gi_r += Pi[base]; gi_z += Pi[base+512]; gi_n += Pi[base+1024];
    }
    {
        size_t base = (size_t)bb*G3 + j;
        gh_r += Ph[base]; gh_z += Ph[base+512]; gh_n += Ph[base+1024];
    }
    float r = sigmoidf_(gi_r + gh_r);
    float z = sigmoidf_(gi_z + gh_z);
    float n = tanhf(gi_n + r*gh_n);
    size_t hoff = (size_t)bb*HDIM + j;
    float hn = (1.f - z)*n + z*h[hoff];
    h[hoff] = hn; hs[j] = hn;
    ushort hh = f2bf_rne(hn);
    Hh[hoff] = hh; Hl[hoff] = f2bf_rne(hn - bf2f(hh));
    __syncthreads();
    // z sample: wave per output; lane reads 32B contiguous of each weight row (coalesced)
    {
        int wv = tid>>6, lane = tid&63;
        const float4* hs4 = (const float4*)hs;
        float4 h0 = hs4[lane*2];
        float4 h1 = hs4[lane*2+1];
        #pragma unroll 4
        for(int it=0; it<16; ++it){
            int jo = wv*16 + it;
            const float4* wm = (const float4*)(Wmu + (size_t)jo*HDIM);
            const float4* wl = (const float4*)(Wls + (size_t)jo*HDIM);
            float4 m0=wm[lane*2], m1=wm[lane*2+1];
            float4 l0=wl[lane*2], l1=wl[lane*2+1];
            float am  = h0.x*m0.x+h0.y*m0.y+h0.z*m0.z+h0.w*m0.w
                      + h1.x*m1.x+h1.y*m1.y+h1.z*m1.z+h1.w*m1.w;
            float al_ = h0.x*l0.x+h0.y*l0.y+h0.z*l0.z+h0.w*l0.w
                      + h1.x*l1.x+h1.y*l1.y+h1.z*l1.z+h1.w*l1.w;
            #pragma unroll
            for(int o=32;o>0;o>>=1){ am += __shfl_down(am,o); al_ += __shfl_down(al_,o); }
            if(lane==0){
                float mu = am + bmu[jo];
                float sg = expf(al_ + bls[jo]);
                float zv = mu + eps_t[(size_t)bb*ZDIM + jo]*sg;
                ushort zh = f2bf_rne(zv);
                Zh[(size_t)bb*ZDIM + jo] = zh;
                Zl[(size_t)bb*ZDIM + jo] = f2bf_rne(zv - bf2f(zh));
            }
        }
    }
}

// dec-i MFMA (Z @ Wid^T, gates r/z/n) fused with decoder GRU combine; 2-product, BK=128
// grid (8 j-col-groups, 4 batch-row-groups); 256 thr
__global__ __launch_bounds__(256) void deci_combine_k(
        const ushort* __restrict__ Zh, const ushort* __restrict__ Zl,
        const ushort* __restrict__ Wid_h,
        const float* __restrict__ Ph2, const float* __restrict__ bi, const float* __restrict__ bh,
        float* __restrict__ h, ushort* __restrict__ Hh, ushort* __restrict__ Hl){
    __shared__ ushort AH[2*64*64], AL[2*64*64], BH[2*64*64];
    int tid = threadIdx.x;
    int lane = tid&63, w = tid>>6;
    int m0 = (w>>1)*32, n0 = (w&1)*32;
    int fr = lane&15, sl = lane>>4;
    int row0 = blockIdx.y*64;           // batch rows
    int jcol0 = blockIdx.x*64;          // hidden j cols (0..511)
    f32x4 acc[3][2][2];
    #pragma unroll
    for(int g=0;g<3;g++)
        #pragma unroll
        for(int i=0;i<2;i++)
            #pragma unroll
            for(int jj=0;jj<2;jj++) acc[g][i][jj]=(f32x4){0.f,0.f,0.f,0.f};
    // A staged once (K=128 fits one buffer)
    stage_swz(Zh, ZDIM, row0, 0,  AH,      tid);
    stage_swz(Zh, ZDIM, row0, 64, AH+4096, tid);
    stage_swz(Zl, ZDIM, row0, 0,  AL,      tid);
    stage_swz(Zl, ZDIM, row0, 64, AL+4096, tid);
    for(int g=0; g<3; ++g){
        if(g>0) __syncthreads();        // prior gate done reading BH
        stage_swz(Wid_h, ZDIM, g*512 + jcol0, 0,  BH,      tid);
        stage_swz(Wid_h, ZDIM, g*512 + jcol0, 64, BH+4096, tid);
        __syncthreads();                // drain (covers A stages on g=0)
        #pragma unroll
        for(int ks=0; ks<4; ks++){
            int slot = ks*4 + sl;
            short8 a_h[2], a_l[2], b_h[2];
            #pragma unroll
            for(int mf=0;mf<2;mf++){
                a_h[mf] = lds_read_swz128(AH, m0+mf*16+fr, slot);
                a_l[mf] = lds_read_swz128(AL, m0+mf*16+fr, slot);
            }
            #pragma unroll
            for(int nf=0;nf<2;nf++)
                b_h[nf] = lds_read_swz128(BH, n0+nf*16+fr, slot);
            #pragma unroll
            for(int mf=0;mf<2;mf++)
                #pragma unroll
                for(int nf=0;nf<2;nf++){
                    acc[g][mf][nf] = __builtin_amdgcn_mfma_f32_16x16x32_bf16(a_h[mf], b_h[nf], acc[g][mf][nf], 0,0,0);
                    acc[g][mf][nf] = __builtin_amdgcn_mfma_f32_16x16x32_bf16(a_l[mf], b_h[nf], acc[g][mf][nf], 0,0,0);
                }
        }
    }
    // epilogue: GRU combine directly from accumulators
    int crow = (lane>>4)*4, ccol = lane&15;
    #pragma unroll
    for(int mf=0;mf<2;mf++)
        #pragma unroll
        for(int nf=0;nf<2;nf++)
            #pragma unroll
            for(int r=0;r<4;r++){
                int row = row0 + m0 + mf*16 + crow + r;     // batch
                int col = jcol0 + n0 + nf*16 + ccol;        // j
                size_t pbase = (size_t)row*G3 + col;
                float gi_r = acc[0][mf][nf][r] + bi[col];
                float gi_z = acc[1][mf][nf][r] + bi[512+col];
                float gi_n = acc[2][mf][nf][r] + bi[1024+col];
                float gh_r = Ph2[pbase]      + bh[col];
                float gh_z = Ph2[pbase+512]  + bh[512+col];
                float gh_n = Ph2[pbase+1024] + bh[1024+col];
                float rr = sigmoidf_(gi_r + gh_r);
                float zz = sigmoidf_(gi_z + gh_z);
                float nn = tanhf(gi_n + rr*gh_n);
                size_t idx = (size_t)row*HDIM + col;
                float hn = (1.f - zz)*nn + zz*h[idx];
                h[idx] = hn;
                ushort hh = f2bf_rne(hn);
                Hh[idx] = hh; Hl[idx] = f2bf_rne(hn - bf2f(hh));
            }
}

// write path: 2 blocks per batch (split by rec row half); reduce(Pw,2 slabs)+apply
// last!=0: apply final sigmoid to rec
__global__ __launch_bounds__(512) void write_apply_k(const float* __restrict__ Pw, const float* __restrict__ b_wr,
        const float* __restrict__ hdec, const float* __restrict__ W_wa, const float* __restrict__ b_wa,
        float* __restrict__ rec, float* __restrict__ s_last, int last){
    __shared__ float sFy[NGRID][ABDIM+1];
    __shared__ float sFx[NGRID][ABDIM+1];
    __shared__ float sw[NGRID][36];
    __shared__ float t[64][36];
    __shared__ float red5[40];
    __shared__ float pp[8];
    int bb = blockIdx.x >> 1, half = blockIdx.x & 1;
    int p0 = half*64;
    int tid = threadIdx.x;
    const float* h = hdec + bb*HDIM;
    attn_params_dev512(h, W_wa, b_wa, red5, pp, tid);
    float invg = expf(-pp[4]);
    fill_fb_R(sFx, sFy, pp, tid);
    for(int i=tid;i<NGRID*NGRID;i+=512){
        float a = b_wr[i];
        #pragma unroll
        for(int s=0;s<2;s++) a += Pw[((size_t)s*BATCHN + bb)*1024 + i];
        sw[i>>5][i&31] = a;
    }
    __syncthreads();
    {
        int pl = tid>>3, iq = tid&7;
        int p = p0 + pl;
        float a[4];
        #pragma unroll
        for(int i=0;i<4;i++) a[i]=0.f;
        for(int j=0;j<NGRID;j++){
            float fy = sFy[j][p];
            float4 w0 = *(const float4*)&sw[j][iq*4];
            a[0]+=fy*w0.x; a[1]+=fy*w0.y; a[2]+=fy*w0.z; a[3]+=fy*w0.w;
        }
        float4 o0; o0.x=a[0];o0.y=a[1];o0.z=a[2];o0.w=a[3];
        *(float4*)&t[pl][iq*4] = o0;
    }
    __syncthreads();
    {
        int q = tid&127, pg = tid>>7;
        float fxc[32];
        #pragma unroll
        for(int i=0;i<32;i++) fxc[i] = sFx[i][q];
        for(int pi=0; pi<16; pi++){
            int pl = pg*16 + pi;
            int p = p0 + pl;
            float acc = 0.f;
            #pragma unroll
            for(int i4=0;i4<8;i4++){
                float4 tv = *(const float4*)&t[pl][i4*4];
                acc += tv.x*fxc[i4*4] + tv.y*fxc[i4*4+1] + tv.z*fxc[i4*4+2] + tv.w*fxc[i4*4+3];
            }
            size_t off = (size_t)bb*IMGSZ + p*ABDIM + q;
            float nv = rec[off] + acc*invg;
            rec[off] = last ? sigmoidf_(nv) : nv;
            if(bb==BATCHN-1) s_last[p*ABDIM + q] = sigmoidf_(nv);
        }
    }
}

extern "C" void kernel_launch(void* const* d_in, const int* in_sizes, int n_in,
                              void* d_out, int out_size, void* d_ws, size_t ws_size,
                              hipStream_t stream) {
    const float* x        = (const float*)d_in[0];
    const float* eps      = (const float*)d_in[1];
    const float* W_ih_enc = (const float*)d_in[2];
    const float* W_hh_enc = (const float*)d_in[3];
    const float* b_ih_enc = (const float*)d_in[4];
    const float* b_hh_enc = (const float*)d_in[5];
    const float* W_ih_dec = (const float*)d_in[6];
    const float* W_hh_dec = (const float*)d_in[7];
    const float* b_ih_dec = (const float*)d_in[8];
    const float* b_hh_dec = (const float*)d_in[9];
    const float* W_mu     = (const float*)d_in[10];
    const float* b_mu     = (const float*)d_in[11];
    const float* W_ls     = (const float*)d_in[12];
    const float* b_ls     = (const float*)d_in[13];
    const float* W_wr     = (const float*)d_in[14];
    const float* b_wr     = (const float*)d_in[15];
    const float* W_ra     = (const float*)d_in[16];
    const float* b_ra     = (const float*)d_in[17];
    const float* W_wa     = (const float*)d_in[18];
    const float* b_wa     = (const float*)d_in[19];

    float* rec = (float*)d_out;

    float* ws = (float*)d_ws;
    float* h_enc  = ws;  ws += BATCHN*HDIM;
    float* h_dec  = ws;  ws += BATCHN*HDIM;
    float* s_last = ws;  ws += IMGSZ;
    float* Pi     = ws;  ws += (size_t)4*SLAB;
    float* Ph     = ws;  ws += (size_t)SLAB;
    float* Ph2    = ws;  ws += (size_t)SLAB;
    float* Pw     = ws;  ws += (size_t)2*BATCHN*1024;

    ushort* us = (ushort*)ws;
    ushort* Wie_h = us; us += 1536*2560;
    ushort* Whe_h = us; us += 1536*512;
    ushort* Whd_h = us; us += 1536*512;
    ushort* Wid_h = us; us += 1536*128;
    ushort* Wwr_h = us; us += 1024*512;
    ushort* Eh    = us; us += BATCHN*ENCIN;
    ushort* El    = us; us += BATCHN*ENCIN;
    ushort* He_h  = us; us += BATCHN*HDIM;
    ushort* He_l  = us; us += BATCHN*HDIM;
    ushort* Hd_h  = us; us += BATCHN*HDIM;
    ushort* Hd_l  = us; us += BATCHN*HDIM;
    ushort* Zh    = us; us += BATCHN*ZDIM;
    ushort* Zl    = us; us += BATCHN*ZDIM;

    hipMemsetAsync(rec,   0, (size_t)BATCHN*IMGSZ*sizeof(float), stream);
    hipMemsetAsync(h_enc, 0, (size_t)BATCHN*HDIM*sizeof(float), stream);
    hipMemsetAsync(h_dec, 0, (size_t)BATCHN*HDIM*sizeof(float), stream);
    hipMemsetAsync(He_h,  0, (size_t)BATCHN*HDIM*sizeof(ushort)*2, stream);  // He_h+He_l contiguous
    hipMemsetAsync(Hd_h,  0, (size_t)BATCHN*HDIM*sizeof(ushort)*2, stream);  // Hd_h+Hd_l contiguous
    init_slast_k<<<IMGSZ/256,256,0,stream>>>(s_last);

    conv_wh_k<<<(1536*2560/4+255)/256,256,0,stream>>>(W_ih_enc, Wie_h, 1536*2560/4);
    conv_wh_k<<<(1536*512/4+255)/256,256,0,stream>>>(W_hh_enc, Whe_h, 1536*512/4);
    conv_wh_k<<<(1536*512/4+255)/256,256,0,stream>>>(W_hh_dec, Whd_h, 1536*512/4);
    conv_wh_k<<<(1536*128/4+255)/256,256,0,stream>>>(W_ih_dec, Wid_h, 1536*128/4);
    conv_wh_k<<<(1024*512/4+255)/256,256,0,stream>>>(W_wr, Wwr_h, 1024*512/4);

    for(int t=0;t<16;t++){
        read_attn_k<<<2*BATCHN,512,0,stream>>>(x, s_last, h_dec, Hd_h, Hd_l, W_ra, b_ra, Eh, El);
        gemm3_k<<<576,256,0,stream>>>(Eh, El, Wie_h, He_h, He_l, Whe_h,
                                      Hd_h, Hd_l, Whd_h, Pi, Ph, Ph2);
        combine_z_k<<<BATCHN,512,0,stream>>>(Pi, Ph, b_ih_enc, b_hh_enc,
            h_enc, He_h, He_l, W_mu, b_mu, W_ls, b_ls, eps + (size_t)t*BATCHN*ZDIM, Zh, Zl);
        deci_combine_k<<<dim3(8,4),256,0,stream>>>(Zh, Zl, Wid_h, Ph2,
            b_ih_dec, b_hh_dec, h_dec, Hd_h, Hd_l);
        gemm_wr_k<<<dim3(16,4,2),256,0,stream>>>(Hd_h, Hd_l, Wwr_h, Pw);
        write_apply_k<<<2*BATCHN,512,0,stream>>>(Pw, b_wr, h_dec, W_wa, b_wa, rec, s_last,
                                                 (t==15)?1:0);
    }
}